// Round 2
// baseline (8301.391 us; speedup 1.0000x reference)
//
#include <hip/hip_runtime.h>
#include <hip/hip_bf16.h>
#include <math.h>
#include <stddef.h>

#define S_LEN 512
#define NBATCH 64
#define HID 1024
#define IN_SZ 1024
#define KTOT 2048        // rows of W: 0..1023 = h, 1024..2047 = x
#define NB 128           // recurrent blocks
#define NCOLS 32         // 4 gates x 8 hidden per block
#define JPB 8

using short8  = __attribute__((ext_vector_type(8))) short;
using floatx4 = __attribute__((ext_vector_type(4))) float;

// ---- workspace layout (bytes) ----
static const size_t WPACK_OFF = 0;
static const size_t XBF_OFF   = 16777216;
static const size_t HBUF_OFF  = XBF_OFF + 67108864;     // 83,886,080
static const size_t FLAGS_OFF = HBUF_OFF + 67239936;    // 151,126,016

__device__ __forceinline__ unsigned short f2b(float f) {
  __hip_bfloat16 h = __float2bfloat16(f);
  return *reinterpret_cast<unsigned short*>(&h);
}
__device__ __forceinline__ float sigm(float z) {
  z = fminf(fmaxf(z, -30.f), 30.f);
  return 1.f / (1.f + __expf(-z));
}
__device__ __forceinline__ float tanh_(float z) {
  z = fminf(fmaxf(z, -15.f), 15.f);
  float e = __expf(2.f * z);
  return (e - 1.f) / (e + 1.f);
}

// ---- prep: transpose W (2048x1024 fp32, k-major rows) -> Wpack[p][c][k] bf16 ----
__global__ void prep_w(const float* __restrict__ Wf, const float* __restrict__ Wi,
                       const float* __restrict__ Wc, const float* __restrict__ Wo,
                       __hip_bfloat16* __restrict__ wpack) {
  __shared__ float tile[64][65];
  const int g = blockIdx.z;
  const float* W = (g == 0) ? Wf : (g == 1) ? Wi : (g == 2) ? Wc : Wo;
  const int k0 = blockIdx.x * 64, j0 = blockIdx.y * 64;
  const int tx = threadIdx.x, ty = threadIdx.y;
  for (int kk = 0; kk < 64; kk += 4)
    tile[kk + ty][tx] = W[(size_t)(k0 + kk + ty) * HID + j0 + tx];
  __syncthreads();
  for (int jj = 0; jj < 64; jj += 4) {
    int j = j0 + jj + ty;
    size_t out = ((size_t)((j >> 3) * NCOLS + g * 8 + (j & 7))) * KTOT + k0 + tx;
    wpack[out] = __float2bfloat16(tile[tx][jj + ty]);
  }
}

// ---- prep: x -> bf16, zero flags ----
__global__ void prep_x(const float* __restrict__ x, unsigned short* __restrict__ xbf,
                       int* __restrict__ flags) {
  size_t i = ((size_t)blockIdx.x * blockDim.x + threadIdx.x) * 4;
  float4 v = *(const float4*)(x + i);
  ushort4 u;
  u.x = f2b(v.x); u.y = f2b(v.y); u.z = f2b(v.z); u.w = f2b(v.w);
  *(ushort4*)(xbf + i) = u;
  if (blockIdx.x == 0 && threadIdx.x < NB) flags[threadIdx.x] = 0;
}

// async global->LDS DMA, 16 B per lane, LDS dest = wave-uniform base + lane*16
#define GLOAD_LDS16(gp, lp)                                                              \
  __builtin_amdgcn_global_load_lds(                                                      \
      (const __attribute__((address_space(1))) unsigned int*)(gp),                       \
      (__attribute__((address_space(3))) unsigned int*)(lp), 16, 0, 0)

// ---- persistent recurrent kernel ----
// Sync protocol (unchanged from round 1, verified correct):
//  * h stores are agent-scope relaxed atomics -> sc1 write-through to LLC.
//  * __syncthreads() (B2) drains vmcnt(0) per wave -> sc1 stores acked at LLC.
//  * flag store relaxed agent AFTER B2 -> readers seeing flag>=t+1 see h data.
//  * reader h addresses are fresh each step -> loads/DMA miss L1/L2, hit LLC.
//
// Round-2 change: h[t] is staged into LDS via global_load_lds DMA.
//  WHY: VGPR_Count stayed 132 in round 1 -> the compiler never materialized
//  deep register staging; the 64 strided h loads issue in small batches,
//  paying ~8-16 serialized LLC round trips per step on the serial chain
//  (the unexplained ~20k cyc of the 28k-cyc step). DMA is fire-and-forget
//  (no VGPR cost), so all 64 x 1KB row-loads are guaranteed in flight at
//  once; one vmcnt wait replaces the round-trip chain.
//  * Each h-wave stages exactly the 64KB K-half it consumes -> no cross-wave
//    staging sync; split vmcnt(32)/vmcnt(0) overlaps m={0,1} MFMAs with the
//    tail of the stream (DMA retires in order).
//  * LDS layout is XOR-swizzled (byte ^= (row&7)<<4) by pre-swizzling the
//    per-lane GLOBAL source address (DMA dest must stay linear); ds_read
//    applies the same XOR -> bank-optimal b128 reads (plain layout would be
//    a 16-way conflict: row stride 1024B == bank-aligned).
//  * LDS budget: 2x64KB staging + 36KB part > 160KB, so part[] aliases
//    wave-0's staging half. Safe: B0 (new barrier) separates all hA reads
//    from all part writes; next-step staging is gated by the flag poll,
//    which postdates every wave's B2 of the previous step.
__launch_bounds__(256, 1)
__global__ void lstm_rec(const unsigned short* __restrict__ xbf,
                         const unsigned short* __restrict__ wpack,
                         const float* __restrict__ bfv, const float* __restrict__ biv,
                         const float* __restrict__ bcv, const float* __restrict__ bov,
                         unsigned short* __restrict__ hbuf,
                         int* __restrict__ flags,
                         float* __restrict__ out) {
  __shared__ __align__(16) unsigned char LDSBUF[131072];  // [0,64K)=wave0 hA (+part alias), [64K,128K)=wave1 hA
  float* partf = (float*)LDSBUF;        // part[4][64][36] aliased at base, 36,864 B
  const int tid  = threadIdx.x;
  const int w    = tid >> 6;            // wave 0..3 ; 0,1 = h-half of K, 2,3 = x-half
  const int lane = tid & 63;
  const int l15  = lane & 15;
  const int lq   = lane >> 4;
  const int p    = blockIdx.x;
  const int j0   = p * JPB;

  // B-operand: this wave's k-quarter of the block's W slice, resident in VGPRs.
  short8 Wreg[32];
  {
    const unsigned short* wp = wpack + (size_t)p * NCOLS * KTOT;
#pragma unroll
    for (int ks = 0; ks < 16; ++ks)
#pragma unroll
      for (int n = 0; n < 2; ++n) {
        int c = n * 16 + l15;
        int k = w * 512 + ks * 32 + lq * 8;
        Wreg[ks * 2 + n] = *(const short8*)(wp + (size_t)c * KTOT + k);
      }
  }
  float bias0, bias1;
  {
    int c = l15;
    bias0 = (c < 8) ? bfv[j0 + c] : biv[j0 + c - 8];
    bias1 = (c < 8) ? bcv[j0 + c] : bov[j0 + c - 8];
  }
  float Cst[4]  = {0.f, 0.f, 0.f, 0.f};
  float hmax[4] = {-__builtin_inff(), -__builtin_inff(), -__builtin_inff(), -__builtin_inff()};
  const int  jj    = l15 & 7;
  const bool act   = (l15 < 8);
  const int  bbase = w * 16 + lq * 4;       // epilogue: wave owns Mtile w
  const bool is_x  = (w >= 2);

  // per-lane constants for swizzled staging / LDS reads
  const unsigned lx   = (unsigned)lane << 4;                                   // DMA src lane offset
  const unsigned vb   = (unsigned)l15 << 10;                                   // ds_read row byte
  const unsigned vcol = ((unsigned)lq << 4) ^ ((unsigned)(l15 & 7) << 4);      // swizzled col base

  for (int t = 0; t < S_LEN; ++t) {
    floatx4 acc[4][2];
#pragma unroll
    for (int m = 0; m < 4; ++m) { acc[m][0] = (floatx4){0,0,0,0}; acc[m][1] = (floatx4){0,0,0,0}; }

    if (is_x) {
      // x-half of K: no dependency, overlaps the h-waves' poll+stage.
      const unsigned short* xa = xbf + (size_t)t * IN_SZ + (w - 2) * 512 + lq * 8;
      short8 a[16][4];
#pragma unroll
      for (int ks = 0; ks < 16; ++ks)
#pragma unroll
        for (int m = 0; m < 4; ++m)
          a[ks][m] = *(const short8*)(xa + (size_t)(m * 16 + l15) * ((size_t)S_LEN * IN_SZ) + ks * 32);
#pragma unroll
      for (int ks = 0; ks < 16; ++ks)
#pragma unroll
        for (int m = 0; m < 4; ++m) {
          acc[m][0] = __builtin_amdgcn_mfma_f32_16x16x32_bf16(a[ks][m], Wreg[ks * 2 + 0], acc[m][0], 0, 0, 0);
          acc[m][1] = __builtin_amdgcn_mfma_f32_16x16x32_bf16(a[ks][m], Wreg[ks * 2 + 1], acc[m][1], 0, 0, 0);
        }
    } else if (t > 0) {
      // wait until every block has published h_buf[t]
      {
        bool ready;
        do {
          int a = __hip_atomic_load(&flags[lane],      __ATOMIC_RELAXED, __HIP_MEMORY_SCOPE_AGENT);
          int b = __hip_atomic_load(&flags[lane + 64], __ATOMIC_RELAXED, __HIP_MEMORY_SCOPE_AGENT);
          ready = __all((a >= t) && (b >= t));
        } while (!ready);
        __atomic_signal_fence(__ATOMIC_ACQUIRE);
        asm volatile("" ::: "memory");   // no hoisting the DMA above the poll
      }
      // ---- stage this wave's 64KB h-half into LDS: 64 x 1KB row DMAs, all in flight.
      // Source address pre-swizzled (lane ^ (row&7)) so LDS holds hA[row][col ^ ((row&7)<<4)].
      const char* gbase = (const char*)(hbuf + (size_t)t * (NBATCH * HID) + (size_t)w * 512);
      char* lbase = (char*)LDSBUF + (w << 16);
#pragma unroll
      for (int i = 0; i < 32; ++i)
        GLOAD_LDS16(gbase + (size_t)i * 2048 + (lx ^ (unsigned)((i & 7) << 4)), lbase + (i << 10));
      __builtin_amdgcn_sched_barrier(0);   // keep rows 0..31 as the oldest 32 in vmcnt order
#pragma unroll
      for (int i = 32; i < 64; ++i)
        GLOAD_LDS16(gbase + (size_t)i * 2048 + (lx ^ (unsigned)((i & 7) << 4)), lbase + (i << 10));

      const char* hAb = (const char*)LDSBUF + (w << 16);
      // rows 0..31 (m-tiles 0,1) ready
      asm volatile("s_waitcnt vmcnt(32)" ::: "memory");
      __builtin_amdgcn_sched_barrier(0);
#pragma unroll
      for (int ks = 0; ks < 16; ++ks) {
        unsigned co = ((unsigned)ks << 6) ^ vcol;
        short8 a0 = *(const short8*)(hAb + vb + co);             // m=0
        short8 a1 = *(const short8*)(hAb + 16384 + vb + co);     // m=1
        acc[0][0] = __builtin_amdgcn_mfma_f32_16x16x32_bf16(a0, Wreg[ks * 2 + 0], acc[0][0], 0, 0, 0);
        acc[0][1] = __builtin_amdgcn_mfma_f32_16x16x32_bf16(a0, Wreg[ks * 2 + 1], acc[0][1], 0, 0, 0);
        acc[1][0] = __builtin_amdgcn_mfma_f32_16x16x32_bf16(a1, Wreg[ks * 2 + 0], acc[1][0], 0, 0, 0);
        acc[1][1] = __builtin_amdgcn_mfma_f32_16x16x32_bf16(a1, Wreg[ks * 2 + 1], acc[1][1], 0, 0, 0);
      }
      // rows 32..63 (m-tiles 2,3) ready
      asm volatile("s_waitcnt vmcnt(0)" ::: "memory");
      __builtin_amdgcn_sched_barrier(0);
#pragma unroll
      for (int ks = 0; ks < 16; ++ks) {
        unsigned co = ((unsigned)ks << 6) ^ vcol;
        short8 a2 = *(const short8*)(hAb + 32768 + vb + co);     // m=2
        short8 a3 = *(const short8*)(hAb + 49152 + vb + co);     // m=3
        acc[2][0] = __builtin_amdgcn_mfma_f32_16x16x32_bf16(a2, Wreg[ks * 2 + 0], acc[2][0], 0, 0, 0);
        acc[2][1] = __builtin_amdgcn_mfma_f32_16x16x32_bf16(a2, Wreg[ks * 2 + 1], acc[2][1], 0, 0, 0);
        acc[3][0] = __builtin_amdgcn_mfma_f32_16x16x32_bf16(a3, Wreg[ks * 2 + 0], acc[3][0], 0, 0, 0);
        acc[3][1] = __builtin_amdgcn_mfma_f32_16x16x32_bf16(a3, Wreg[ks * 2 + 1], acc[3][1], 0, 0, 0);
      }
    }
    // B0: all hA reads done before anyone touches the aliased part[] region
    __syncthreads();
    // publish partials: part[w][lane][m*8 + n*4 + r], stride 36 floats
    {
      float* pr = partf + (size_t)(w * 64 + lane) * 36;
#pragma unroll
      for (int m = 0; m < 4; ++m) {
        *(floatx4*)(pr + m * 8 + 0) = acc[m][0];
        *(floatx4*)(pr + m * 8 + 4) = acc[m][1];
      }
    }
    __syncthreads();   // B1
    // reduce my Mtile (=w) across the 4 k-quarters
    floatx4 r0 = {0, 0, 0, 0}, r1 = {0, 0, 0, 0};
#pragma unroll
    for (int sw = 0; sw < 4; ++sw) {
      const float* q = partf + (size_t)(sw * 64 + lane) * 36 + w * 8;
      r0 += *(const floatx4*)(q);
      r1 += *(const floatx4*)(q + 4);
    }
    // epilogue: C/D layout col=l15, row=lq*4+r. cols 0..7=f,8..15=i | 16..23=c,24..31=o
#pragma unroll
    for (int r = 0; r < 4; ++r) {
      float g0  = r0[r] + bias0;
      float g1  = r1[r] + bias1;
      float g0o = __shfl_xor(g0, 8);
      float g1o = __shfl_xor(g1, 8);
      float fg = sigm(g0);        // valid on lanes l15<8
      float ig = sigm(g0o);
      float cg = tanh_(g1);
      float og = sigm(g1o);
      float C  = fg * Cst[r] + ig * cg;
      Cst[r] = C;
      float h = og * tanh_(C);
      int b = bbase + r;
      if (act)
        __builtin_nontemporal_store(
            h, &out[(size_t)b * ((size_t)S_LEN * HID) + (size_t)t * HID + j0 + jj]);
      float hm = fmaxf(hmax[r], h);
      hmax[r] = hm;
      // publish running max as next-step hidden (bf16 pairs, sc1 stores)
      unsigned int hb    = f2b(hm);
      unsigned int other = (unsigned int)__shfl_xor((int)hb, 1) & 0xffffu;
      if (act && ((jj & 1) == 0)) {
        unsigned int word = hb | (other << 16);
        unsigned int* dst = (unsigned int*)(hbuf + (size_t)(t + 1) * (NBATCH * HID) + (size_t)b * HID + j0 + jj);
        __hip_atomic_store(dst, word, __ATOMIC_RELAXED, __HIP_MEMORY_SCOPE_AGENT);
      }
    }
    __syncthreads();   // B2: vmcnt(0) per wave -> sc1 h-stores acked at LLC
    if (tid == 0)
      __hip_atomic_store(&flags[p], t + 1, __ATOMIC_RELAXED, __HIP_MEMORY_SCOPE_AGENT);
  }
  // finals: h_fin = running max, C_fin
  const size_t HSEQ = (size_t)NBATCH * S_LEN * HID;
#pragma unroll
  for (int r = 0; r < 4; ++r) {
    int b = bbase + r;
    if (act) {
      __builtin_nontemporal_store(hmax[r], &out[HSEQ + (size_t)b * HID + j0 + jj]);
      __builtin_nontemporal_store(Cst[r],  &out[HSEQ + (size_t)NBATCH * HID + (size_t)b * HID + j0 + jj]);
    }
  }
}

extern "C" void kernel_launch(void* const* d_in, const int* in_sizes, int n_in,
                              void* d_out, int out_size, void* d_ws, size_t ws_size,
                              hipStream_t stream) {
  const float* x   = (const float*)d_in[0];
  const float* Wf  = (const float*)d_in[1];
  const float* bf_ = (const float*)d_in[2];
  const float* Wi  = (const float*)d_in[3];
  const float* bi_ = (const float*)d_in[4];
  const float* Wc  = (const float*)d_in[5];
  const float* bc_ = (const float*)d_in[6];
  const float* Wo  = (const float*)d_in[7];
  const float* bo_ = (const float*)d_in[8];
  char* ws = (char*)d_ws;
  __hip_bfloat16* wpack_bf = (__hip_bfloat16*)(ws + WPACK_OFF);
  unsigned short* xbf      = (unsigned short*)(ws + XBF_OFF);
  unsigned short* hbuf     = (unsigned short*)(ws + HBUF_OFF);
  int* flags               = (int*)(ws + FLAGS_OFF);
  float* outp              = (float*)d_out;

  hipLaunchKernelGGL(prep_w, dim3(KTOT / 64, HID / 64, 4), dim3(64, 4, 1), 0, stream,
                     Wf, Wi, Wc, Wo, wpack_bf);
  hipLaunchKernelGGL(prep_x, dim3(32768), dim3(256), 0, stream, x, xbf, flags);

  lstm_rec<<<dim3(NB), dim3(256), 0, stream>>>(
      xbf, (const unsigned short*)wpack_bf, bf_, bi_, bc_, bo_, hbuf, flags, outp);
}

// Round 4
// 5684.626 us; speedup vs baseline: 1.4603x; 1.4603x over previous
//
#include <hip/hip_runtime.h>
#include <hip/hip_bf16.h>
#include <math.h>
#include <stddef.h>

#define S_LEN 512
#define NBATCH 64
#define HID 1024
#define IN_SZ 1024
#define KTOT 2048        // rows of W: 0..1023 = h, 1024..2047 = x
#define NB 128           // recurrent blocks
#define NCOLS 32         // 4 gates x 8 hidden per block
#define JPB 8

using short8  = __attribute__((ext_vector_type(8))) short;
using floatx4 = __attribute__((ext_vector_type(4))) float;

// ---- workspace layout (bytes) ----
static const size_t WPACK_OFF = 0;
static const size_t XBF_OFF   = 16777216;
static const size_t HBUF_OFF  = XBF_OFF + 67108864;     // 83,886,080
static const size_t FLAGS_OFF = HBUF_OFF + 67239936;    // 151,126,016

__device__ __forceinline__ unsigned short f2b(float f) {
  __hip_bfloat16 h = __float2bfloat16(f);
  return *reinterpret_cast<unsigned short*>(&h);
}
__device__ __forceinline__ float sigm(float z) {
  z = fminf(fmaxf(z, -30.f), 30.f);
  return 1.f / (1.f + __expf(-z));
}
__device__ __forceinline__ float tanh_(float z) {
  z = fminf(fmaxf(z, -15.f), 15.f);
  float e = __expf(2.f * z);
  return (e - 1.f) / (e + 1.f);
}

// ---- prep: transpose W (2048x1024 fp32, k-major rows) -> Wpack[p][c][k] bf16 ----
__global__ void prep_w(const float* __restrict__ Wf, const float* __restrict__ Wi,
                       const float* __restrict__ Wc, const float* __restrict__ Wo,
                       __hip_bfloat16* __restrict__ wpack) {
  __shared__ float tile[64][65];
  const int g = blockIdx.z;
  const float* W = (g == 0) ? Wf : (g == 1) ? Wi : (g == 2) ? Wc : Wo;
  const int k0 = blockIdx.x * 64, j0 = blockIdx.y * 64;
  const int tx = threadIdx.x, ty = threadIdx.y;
  for (int kk = 0; kk < 64; kk += 4)
    tile[kk + ty][tx] = W[(size_t)(k0 + kk + ty) * HID + j0 + tx];
  __syncthreads();
  for (int jj = 0; jj < 64; jj += 4) {
    int j = j0 + jj + ty;
    size_t out = ((size_t)((j >> 3) * NCOLS + g * 8 + (j & 7))) * KTOT + k0 + tx;
    wpack[out] = __float2bfloat16(tile[tx][jj + ty]);
  }
}

// ---- prep: x -> bf16, zero flags ----
__global__ void prep_x(const float* __restrict__ x, unsigned short* __restrict__ xbf,
                       int* __restrict__ flags) {
  size_t i = ((size_t)blockIdx.x * blockDim.x + threadIdx.x) * 4;
  float4 v = *(const float4*)(x + i);
  ushort4 u;
  u.x = f2b(v.x); u.y = f2b(v.y); u.z = f2b(v.z); u.w = f2b(v.w);
  *(ushort4*)(xbf + i) = u;
  if (blockIdx.x == 0 && threadIdx.x < NB) flags[threadIdx.x] = 0;
}

// ---- persistent recurrent kernel ----
// Sync protocol (round-1 verified, store path reworked in round 3):
//  * hbuf stores are agent-scope relaxed u32 atomics -> sc1 write-through to
//    LLC, never dirty in a local L2.
//  * B2 __syncthreads drains vmcnt(0) per wave -> hbuf stores acked at LLC.
//  * flag store (relaxed agent) AFTER B2 -> readers seeing flag>=t+1 are
//    guaranteed h[t+1] is at the LLC.
//  * reader h addresses are fresh each step -> plain loads miss L1/L2 and
//    fetch the LLC copy.
//
// Round-3 changes (counter evidence: FETCH_SIZE 539 MB vs 147 MB unique read
// set = ~390 MB of read-modify-write amplification from sub-line stores; the
// scattered-store ack chain also sat on the pre-flag drain):
//  1. hbuf re-layout: [t][j_octet p][batch 64][col 8] bf16 -> each block's
//     per-step h slice is ONE contiguous 1 KB run. Published via LDS repack:
//     epilogue -> hsl[] scratch -> B1 -> all 256 threads store one u32 each
//     (per-wave 256 B fully-coalesced sc1 stores, full-line at the LLC, no
//     RMW). Readers get 256 B-coalesced h loads (16 lanes x 16 B contiguous)
//     instead of 64 B segments.
//  2. out stores moved OFF the pre-flag critical path: fp32 h repacked into
//     osl[] scratch; after the flag is raised the x-waves store out as
//     nontemporal 16B vectors, which drain during the next step's
//     x-load/MFMA phase (plenty of slack before their next draining barrier).
//  3. Flag poll is one 8 B atomic load (covers 2 flags/lane) instead of two.
//  (Round-2's global_load_lds staging + XOR swizzle REVERTED: it serialized
//   the chain behind vmcnt waits and its swizzle was 8-way-conflicted --
//   dur 6210 -> 8301 us, SQ_LDS_BANK_CONFLICT 0 -> 3.3e7.)
//  Round-3b: __builtin_nontemporal_store needs ext_vector_type, not HIP
//  float4 (compile fix only).
__launch_bounds__(256, 1)
__global__ void lstm_rec(const unsigned short* __restrict__ xbf,
                         const unsigned short* __restrict__ wpack,
                         const float* __restrict__ bfv, const float* __restrict__ biv,
                         const float* __restrict__ bcv, const float* __restrict__ bov,
                         unsigned short* __restrict__ hbuf,
                         int* __restrict__ flags,
                         float* __restrict__ out) {
  __shared__ float part[4][64][36];          // [wave][lane][m*8+n*4+r], stride 36 for banking
  __shared__ unsigned short hsl[NBATCH * JPB];   // 1 KB: bf16 running-max slice [b][jj]
  __shared__ float          osl[NBATCH * JPB];   // 2 KB: fp32 raw-h slice [b][jj]
  const int tid  = threadIdx.x;
  const int w    = tid >> 6;          // wave 0..3 ; 0,1 = h-half of K, 2,3 = x-half
  const int lane = tid & 63;
  const int l15  = lane & 15;
  const int lq   = lane >> 4;
  const int p    = blockIdx.x;
  const int j0   = p * JPB;

  // B-operand: this wave's k-quarter of the block's W slice, resident in VGPRs.
  short8 Wreg[32];
  {
    const unsigned short* wp = wpack + (size_t)p * NCOLS * KTOT;
#pragma unroll
    for (int ks = 0; ks < 16; ++ks)
#pragma unroll
      for (int n = 0; n < 2; ++n) {
        int c = n * 16 + l15;
        int k = w * 512 + ks * 32 + lq * 8;
        Wreg[ks * 2 + n] = *(const short8*)(wp + (size_t)c * KTOT + k);
      }
  }
  float bias0, bias1;
  {
    int c = l15;
    bias0 = (c < 8) ? bfv[j0 + c] : biv[j0 + c - 8];
    bias1 = (c < 8) ? bcv[j0 + c] : bov[j0 + c - 8];
  }
  float Cst[4]  = {0.f, 0.f, 0.f, 0.f};
  float hmax[4] = {-__builtin_inff(), -__builtin_inff(), -__builtin_inff(), -__builtin_inff()};
  const int  jj    = l15 & 7;
  const bool act   = (l15 < 8);
  const int  bbase = w * 16 + lq * 4;       // epilogue: wave owns Mtile w
  const bool is_x  = (w >= 2);

  for (int t = 0; t < S_LEN; ++t) {
    floatx4 acc[4][2];
#pragma unroll
    for (int m = 0; m < 4; ++m) { acc[m][0] = (floatx4){0,0,0,0}; acc[m][1] = (floatx4){0,0,0,0}; }

    if (is_x) {
      // x-half of K: no dependency, runs before the sync point
      const unsigned short* xa = xbf + (size_t)t * IN_SZ + (w - 2) * 512 + lq * 8;
#pragma unroll
      for (int ks = 0; ks < 16; ++ks) {
        short8 a[4];
#pragma unroll
        for (int m = 0; m < 4; ++m)
          a[m] = *(const short8*)(xa + (size_t)(m * 16 + l15) * ((size_t)S_LEN * IN_SZ) + ks * 32);
#pragma unroll
        for (int m = 0; m < 4; ++m) {
          acc[m][0] = __builtin_amdgcn_mfma_f32_16x16x32_bf16(a[m], Wreg[ks * 2 + 0], acc[m][0], 0, 0, 0);
          acc[m][1] = __builtin_amdgcn_mfma_f32_16x16x32_bf16(a[m], Wreg[ks * 2 + 1], acc[m][1], 0, 0, 0);
        }
      }
    } else if (t > 0) {
      // wait until every block has published h_buf[t] (one 8B atomic load
      // covers flags[2*lane] and flags[2*lane+1]; relaxed: no buffer_inv)
      {
        bool ready;
        do {
          long long ff = __hip_atomic_load((const long long*)flags + lane,
                                           __ATOMIC_RELAXED, __HIP_MEMORY_SCOPE_AGENT);
          int a = (int)ff, b = (int)(ff >> 32);
          ready = __all((a >= t) && (b >= t));
        } while (!ready);
        __atomic_signal_fence(__ATOMIC_ACQUIRE);   // compiler-only: no hoisting h loads
      }
      // h loads from the octet-packed layout: per (ks,m) instruction the 16
      // l15-lanes read 256 B contiguous (4 chunks at 1 KB stride across lq).
      const unsigned short* hab = hbuf + (size_t)t * (NBATCH * HID)
                                 + (size_t)w * 32768 + (size_t)lq * 512 + (size_t)l15 * 8;
#pragma unroll
      for (int ks = 0; ks < 16; ++ks) {
        short8 a[4];
#pragma unroll
        for (int m = 0; m < 4; ++m)
          a[m] = *(const short8*)(hab + ks * 2048 + m * 128);
#pragma unroll
        for (int m = 0; m < 4; ++m) {
          acc[m][0] = __builtin_amdgcn_mfma_f32_16x16x32_bf16(a[m], Wreg[ks * 2 + 0], acc[m][0], 0, 0, 0);
          acc[m][1] = __builtin_amdgcn_mfma_f32_16x16x32_bf16(a[m], Wreg[ks * 2 + 1], acc[m][1], 0, 0, 0);
        }
      }
    }
    // publish partials
#pragma unroll
    for (int m = 0; m < 4; ++m) {
      *(floatx4*)&part[w][lane][m * 8 + 0] = acc[m][0];
      *(floatx4*)&part[w][lane][m * 8 + 4] = acc[m][1];
    }
    __syncthreads();   // B0
    // reduce my Mtile (=w) across the 4 k-quarters
    floatx4 r0 = {0, 0, 0, 0}, r1 = {0, 0, 0, 0};
#pragma unroll
    for (int sw = 0; sw < 4; ++sw) {
      r0 += *(const floatx4*)&part[sw][lane][w * 8 + 0];
      r1 += *(const floatx4*)&part[sw][lane][w * 8 + 4];
    }
    // epilogue: C/D layout col=l15, row=lq*4+r. cols 0..7=f,8..15=i | 16..23=c,24..31=o
#pragma unroll
    for (int r = 0; r < 4; ++r) {
      float g0  = r0[r] + bias0;
      float g1  = r1[r] + bias1;
      float g0o = __shfl_xor(g0, 8);
      float g1o = __shfl_xor(g1, 8);
      float fg = sigm(g0);        // valid on lanes l15<8
      float ig = sigm(g0o);
      float cg = tanh_(g1);
      float og = sigm(g1o);
      float C  = fg * Cst[r] + ig * cg;
      Cst[r] = C;
      float h = og * tanh_(C);
      float hm = fmaxf(hmax[r], h);
      hmax[r] = hm;
      if (act) {
        int b = bbase + r;
        osl[b * JPB + l15] = h;          // raw h -> out (stored post-flag)
        hsl[b * JPB + l15] = f2b(hm);    // running max -> next-step hidden
      }
    }
    __syncthreads();   // B1: hsl/osl complete
    // coalesced h publish: 256 threads x u32 = the block's contiguous 1 KB
    // octet slab hbuf[t+1][p][*][*]; per-wave 256 B fully coalesced.
    {
      unsigned word = *((const unsigned*)hsl + tid);
      unsigned* dst = (unsigned*)(hbuf + (size_t)(t + 1) * (NBATCH * HID)
                                  + (size_t)p * 512) + tid;
      __hip_atomic_store(dst, word, __ATOMIC_RELAXED, __HIP_MEMORY_SCOPE_AGENT);
    }
    __syncthreads();   // B2: vmcnt(0) per wave -> all hbuf stores acked at LLC
    if (tid == 0)
      __hip_atomic_store(&flags[p], t + 1, __ATOMIC_RELAXED, __HIP_MEMORY_SCOPE_AGENT);
    // out stores: off the critical path (after flag). x-waves only; they
    // drain during the next step's x-load/MFMA phase.
    if (is_x) {
      int q    = tid - 128;            // 0..127
      int b    = q >> 1;
      int half = q & 1;
      floatx4 v = *(const floatx4*)&osl[b * JPB + half * 4];
      __builtin_nontemporal_store(
          v, (floatx4*)&out[(size_t)b * ((size_t)S_LEN * HID) + (size_t)t * HID + j0 + half * 4]);
    }
  }
  // finals: h_fin = running max, C_fin
  const size_t HSEQ = (size_t)NBATCH * S_LEN * HID;
#pragma unroll
  for (int r = 0; r < 4; ++r) {
    int b = bbase + r;
    if (act) {
      __builtin_nontemporal_store(hmax[r], &out[HSEQ + (size_t)b * HID + j0 + jj]);
      __builtin_nontemporal_store(Cst[r],  &out[HSEQ + (size_t)NBATCH * HID + (size_t)b * HID + j0 + jj]);
    }
  }
}

extern "C" void kernel_launch(void* const* d_in, const int* in_sizes, int n_in,
                              void* d_out, int out_size, void* d_ws, size_t ws_size,
                              hipStream_t stream) {
  const float* x   = (const float*)d_in[0];
  const float* Wf  = (const float*)d_in[1];
  const float* bf_ = (const float*)d_in[2];
  const float* Wi  = (const float*)d_in[3];
  const float* bi_ = (const float*)d_in[4];
  const float* Wc  = (const float*)d_in[5];
  const float* bc_ = (const float*)d_in[6];
  const float* Wo  = (const float*)d_in[7];
  const float* bo_ = (const float*)d_in[8];
  char* ws = (char*)d_ws;
  __hip_bfloat16* wpack_bf = (__hip_bfloat16*)(ws + WPACK_OFF);
  unsigned short* xbf      = (unsigned short*)(ws + XBF_OFF);
  unsigned short* hbuf     = (unsigned short*)(ws + HBUF_OFF);
  int* flags               = (int*)(ws + FLAGS_OFF);
  float* outp              = (float*)d_out;

  hipLaunchKernelGGL(prep_w, dim3(KTOT / 64, HID / 64, 4), dim3(64, 4, 1), 0, stream,
                     Wf, Wi, Wc, Wo, wpack_bf);
  hipLaunchKernelGGL(prep_x, dim3(32768), dim3(256), 0, stream, x, xbf, flags);

  lstm_rec<<<dim3(NB), dim3(256), 0, stream>>>(
      xbf, (const unsigned short*)wpack_bf, bf_, bi_, bc_, bo_, hbuf, flags, outp);
}